// Round 12
// baseline (53.047 us; speedup 1.0000x reference)
//
#include <hip/hip_runtime.h>
#include <hip/hip_bf16.h>

using bf16x8 = __attribute__((ext_vector_type(8))) short;
using bf16x4 = __attribute__((ext_vector_type(4))) short;
using f32x4  = __attribute__((ext_vector_type(4))) float;

namespace {
constexpr int nB = 128, nS = 300, nC = 64, nH = 768, nM = 300;
constexpr int MT  = 160;            // m-tile per block (2 blocks per b)
constexpr int KC  = 32;             // k chunk
constexpr int NKC = nH / KC;        // 24
// LDS (bytes). K-loop: FOUR staging buffers [0, 139264) -> 1 barrier / 2 chunks.
// Post-K-loop overlays (all bufs dead): GTS [0,49152); after PV: W2R [0,44032).
// RED1/RED2/MASK live past the buffers (disjoint from everything).
constexpr int BUFSZ    = 34816;     // ctx 20480 + pos 10240 + resp 4096
constexpr int STG_CTX  = 0;         // [320 s][64 B] bf16 chunk, XOR-swizzled
constexpr int STG_POS  = 20480;     // [160 m][64 B]
constexpr int STG_RESP = 30720;     // [64 c][64 B]
constexpr int GTSOF    = 0;         // [64 c][768 B] bf16, XOR (c&15)<<3
constexpr int W2R      = 0;         // [64 c][172 f32] (post-PV only)
constexpr int RED1     = 139264;    // 2560 B (softmax max / final fred)
constexpr int RED2     = 141824;    // 2560 B (softmax sum)
constexpr int MASKOF   = 144384;    // 320 f32 = 1280 B
constexpr int LDSB     = 145664;
}

// fp32 -> packed 2x bf16 RNE via HIP intrinsic (round-11-proven: cut VALU 18->14%)
__device__ __forceinline__ unsigned pack2(float a, float b) {
    float2 f2; f2.x = a; f2.y = b;
    __hip_bfloat162 h2 = __float22bfloat162_rn(f2);
    unsigned u;
    __builtin_memcpy(&u, &h2, 4);
    return u;
}
__device__ __forceinline__ uint2 cvt4(float4 v) {
    return make_uint2(pack2(v.x, v.y), pack2(v.z, v.w));
}
// staging swizzle (64B rows): slot XOR (r>>1)&3 -> over 8 consecutive rows the
// bank-quad (4r + slot) mod 8 hits all 8 quads; 16-lane frag reads land
// 2 lanes/quad = conflict-free (verified round 8: 2.56M -> 205K).
__device__ __forceinline__ int swz(int row, int bcol) {
    return row * 64 + (bcol ^ (((row >> 1) & 3) << 4));
}
// GTS swizzle: pitch 768, XOR spreads column accesses across all 32 banks
__device__ __forceinline__ int gts(int c, int bs) {   // bs = 2*s
    return GTSOF + c * 768 + (bs ^ ((c & 15) << 3));
}

__device__ __forceinline__ f32x4 mfma16(bf16x4 a, bf16x4 b, f32x4 c) {
#if __has_builtin(__builtin_amdgcn_mfma_f32_16x16x16bf16_1k)
    return __builtin_amdgcn_mfma_f32_16x16x16bf16_1k(a, b, c, 0, 0, 0);
#else
    asm volatile("v_mfma_f32_16x16x16_bf16 %0, %1, %2, %0"
                 : "+v"(c) : "v"(a), "v"(b));
    return c;
#endif
}

// ---------------------------------------------------------------------------
// One block per (b, m-half). 512 threads = 8 waves: wave = (sg 0..3, mg 0..1).
// K-loop: quad-buffered KC=32 chunks, ONE barrier per TWO chunks. Pair i:
//   stage(2i+2) -> loads(2i+3) -> compute(2i) -> stage(2i+3) -> loads(2i+4)
//   -> compute(2i+1) -> barrier. Hazards fenced by the pair-(i-1) barrier.
// Then: GtS write, in-register masked softmax, PV with in-register P A-frags,
//   ordered cross-wave w2 reduce, square-sum, one atomic per (block, c).
// ---------------------------------------------------------------------------
__global__ __launch_bounds__(512, 2) void fused(const float* __restrict__ ctx,
                                                const float* __restrict__ resp,
                                                const float* __restrict__ pos,
                                                const int*  __restrict__ mask,
                                                float* __restrict__ out) {
    extern __shared__ char sm[];
    const int b   = blockIdx.x & 127;
    const int mh  = blockIdx.x >> 7;
    const int m0  = mh * MT;
    const int tid = threadIdx.x;
    const int ln  = tid & 63, wv = tid >> 6;
    const int l15 = ln & 15, g = ln >> 4;
    const int sg  = wv & 3, mg = wv >> 2;

    const float* __restrict__ ctxb  = ctx  + (size_t)b * nS * nH;
    const float* __restrict__ respb = resp + (size_t)b * nC * nH;

    // hoisted per-thread load pointers (advance by k0 only)
    const float* pcx[5];
    #pragma unroll
    for (int i = 0; i < 5; ++i) {
        int q = i * 512 + tid, r = q >> 3, kq = q & 7;
        int s = (r < nS) ? r : (nS - 1);
        pcx[i] = ctxb + (size_t)s * nH + kq * 4;
    }
    const float* ppx[3];
    #pragma unroll
    for (int i = 0; i < 3; ++i) {
        int q = i * 512 + tid, r = q >> 3, kq = q & 7;
        int m = m0 + r; if (m >= nM) m = nM - 1;
        ppx[i] = pos + (size_t)m * nH + kq * 4;
    }
    const float* prx = respb + (size_t)(tid >> 3) * nH + (tid & 7) * 4;

    // mask -> LDS (read after K-loop; region never overlaid)
    float* maskS = (float*)(sm + MASKOF);
    if (tid < 320) maskS[tid] = (tid < nS) ? (float)mask[b * nS + tid] : 0.f;

    f32x4 acc[5][5];    // logits: D[s(sj)][m(mj)] swapped
    f32x4 gacc[5][2];   // G: D[s(sj)][c(cj within mg pair)]
    #pragma unroll
    for (int i = 0; i < 5; ++i) {
        #pragma unroll
        for (int j = 0; j < 5; ++j) acc[i][j] = (f32x4){0.f, 0.f, 0.f, 0.f};
        gacc[i][0] = (f32x4){0.f, 0.f, 0.f, 0.f};
        gacc[i][1] = (f32x4){0.f, 0.f, 0.f, 0.f};
    }

    float4 cR[5], pR[3], rR;
    auto loads = [&](int t) {
        const int k0 = t * KC;
        #pragma unroll
        for (int i = 0; i < 5; ++i) cR[i] = *(const float4*)(pcx[i] + k0);
        #pragma unroll
        for (int i = 0; i < 3; ++i)
            if (i * 512 + tid < 1280) pR[i] = *(const float4*)(ppx[i] + k0);
        rR = *(const float4*)(prx + k0);
    };
    auto stage = [&](char* base) {
        #pragma unroll
        for (int i = 0; i < 5; ++i) {
            int q = i * 512 + tid, r = q >> 3, kq = q & 7;
            *(uint2*)(base + STG_CTX + swz(r, kq * 8)) = cvt4(cR[i]);
        }
        #pragma unroll
        for (int i = 0; i < 3; ++i) {
            int q = i * 512 + tid;
            if (q < 1280) {
                int r = q >> 3, kq = q & 7;
                *(uint2*)(base + STG_POS + swz(r, kq * 8)) = cvt4(pR[i]);
            }
        }
        { int r = tid >> 3, kq = tid & 7;
          *(uint2*)(base + STG_RESP + swz(r, kq * 8)) = cvt4(rR); }
    };
    auto compute = [&](const char* rbase) {
        bf16x8 fp[5], fr[2];
        #pragma unroll
        for (int mj = 0; mj < 5; ++mj) {
            int r = 80 * mg + 16 * mj + l15;
            fp[mj] = *(const bf16x8*)(rbase + STG_POS + swz(r, g * 16));
        }
        #pragma unroll
        for (int cj = 0; cj < 2; ++cj) {
            int r = 16 * (2 * mg + cj) + l15;
            fr[cj] = *(const bf16x8*)(rbase + STG_RESP + swz(r, g * 16));
        }
        #pragma unroll
        for (int sj = 0; sj < 5; ++sj) {
            int r = 80 * sg + 16 * sj + l15;
            bf16x8 fa = *(const bf16x8*)(rbase + STG_CTX + swz(r, g * 16));
            #pragma unroll
            for (int mj = 0; mj < 5; ++mj)
                acc[sj][mj] = __builtin_amdgcn_mfma_f32_16x16x32_bf16(fa, fp[mj], acc[sj][mj], 0, 0, 0);
            #pragma unroll
            for (int cj = 0; cj < 2; ++cj)
                gacc[sj][cj] = __builtin_amdgcn_mfma_f32_16x16x32_bf16(fa, fr[cj], gacc[sj][cj], 0, 0, 0);
        }
    };

    // prologue: fill buf0,buf1 (chunks 0,1); chunk 2 in regs
    loads(0); stage(sm + 0 * BUFSZ);
    loads(1); stage(sm + 1 * BUFSZ);
    loads(2);
    __syncthreads();

    for (int i = 0; i < NKC / 2; ++i) {
        char* bA = sm + (((2 * i) & 3) * BUFSZ);
        char* bB = sm + (((2 * i + 1) & 3) * BUFSZ);
        char* bC = sm + (((2 * i + 2) & 3) * BUFSZ);
        char* bD = sm + (((2 * i + 3) & 3) * BUFSZ);
        if (2 * i + 2 < NKC) stage(bC);
        if (2 * i + 3 < NKC) loads(2 * i + 3);
        compute(bA);
        if (2 * i + 3 < NKC) stage(bD);
        if (2 * i + 4 < NKC) loads(2 * i + 4);
        compute(bB);
        __syncthreads();   // pair's reads done; staged bufs visible
    }

    // ---- GtS[c][s] bf16 (staging dead; overlays buffers) ----
    #pragma unroll
    for (int sj = 0; sj < 5; ++sj)
        #pragma unroll
        for (int cj = 0; cj < 2; ++cj) {
            int c = 16 * (2 * mg + cj) + l15;
            int s = 80 * sg + 16 * sj + 4 * g;
            *(uint2*)(sm + gts(c, 2 * s)) =
                make_uint2(pack2(gacc[sj][cj][0], gacc[sj][cj][1]),
                           pack2(gacc[sj][cj][2], gacc[sj][cj][3]));
        }

    // ---- multiplicative mask (from LDS); pad s rows -> -inf ----
    #pragma unroll
    for (int sj = 0; sj < 5; ++sj)
        #pragma unroll
        for (int r = 0; r < 4; ++r) {
            int s = 80 * sg + 16 * sj + 4 * g + r;
            if (s < nS) {
                float mv = maskS[s];
                #pragma unroll
                for (int mj = 0; mj < 5; ++mj) acc[sj][mj][r] *= mv;
            } else {
                #pragma unroll
                for (int mj = 0; mj < 5; ++mj) acc[sj][mj][r] = -1e30f;
            }
        }

    // ---- softmax over s: in-reg 20-reduce + shfl + LDS across 4 s-waves ----
    float* red1 = (float*)(sm + RED1);
    float* red2 = (float*)(sm + RED2);
    float inv[5];
    {
        float mx[5];
        #pragma unroll
        for (int mj = 0; mj < 5; ++mj) {
            float m = -1e30f;
            #pragma unroll
            for (int sj = 0; sj < 5; ++sj)
                #pragma unroll
                for (int r = 0; r < 4; ++r) m = fmaxf(m, acc[sj][mj][r]);
            m = fmaxf(m, __shfl_xor(m, 16));
            m = fmaxf(m, __shfl_xor(m, 32));
            mx[mj] = m;
        }
        if (ln < 16) {
            #pragma unroll
            for (int mj = 0; mj < 5; ++mj) red1[sg * 160 + 80 * mg + 16 * mj + ln] = mx[mj];
        }
        __syncthreads();   // also publishes GtS writes for PV
        float m4[5];
        #pragma unroll
        for (int mj = 0; mj < 5; ++mj) {
            int idx = 80 * mg + 16 * mj + l15;
            m4[mj] = fmaxf(fmaxf(red1[idx], red1[160 + idx]),
                           fmaxf(red1[320 + idx], red1[480 + idx]));
        }
        float sum[5];
        #pragma unroll
        for (int mj = 0; mj < 5; ++mj) {
            float s = 0.f;
            #pragma unroll
            for (int sj = 0; sj < 5; ++sj)
                #pragma unroll
                for (int r = 0; r < 4; ++r) {
                    float e = __expf(acc[sj][mj][r] - m4[mj]);
                    acc[sj][mj][r] = e;
                    s += e;
                }
            s += __shfl_xor(s, 16);
            s += __shfl_xor(s, 32);
            sum[mj] = s;
        }
        if (ln < 16) {
            #pragma unroll
            for (int mj = 0; mj < 5; ++mj) red2[sg * 160 + 80 * mg + 16 * mj + ln] = sum[mj];
        }
        __syncthreads();
        #pragma unroll
        for (int mj = 0; mj < 5; ++mj) {
            int idx = 80 * mg + 16 * mj + l15;
            float tt = red2[idx] + red2[160 + idx] + red2[320 + idx] + red2[480 + idx];
            int mglob = m0 + 80 * mg + 16 * mj + l15;
            inv[mj] = (mglob < nM) ? (1.0f / tt) : 0.0f;   // pad m rows -> P = 0
        }
    }

    // ---- P in-register (16x16x16 A-layout: k = 4*g + j matches swapped C) ----
    union PU { uint2 u; bf16x4 v; };
    bf16x4 P[5][5];
    #pragma unroll
    for (int sj = 0; sj < 5; ++sj)
        #pragma unroll
        for (int mj = 0; mj < 5; ++mj) {
            PU pu;
            pu.u = make_uint2(pack2(acc[sj][mj][0] * inv[mj], acc[sj][mj][1] * inv[mj]),
                              pack2(acc[sj][mj][2] * inv[mj], acc[sj][mj][3] * inv[mj]));
            P[sj][mj] = pu.v;
        }

    // ---- PV: partial w2 over this wave's s-range ----
    f32x4 pacc[5][4];
    #pragma unroll
    for (int mj = 0; mj < 5; ++mj)
        #pragma unroll
        for (int cj = 0; cj < 4; ++cj) pacc[mj][cj] = (f32x4){0.f, 0.f, 0.f, 0.f};
    #pragma unroll
    for (int sj = 0; sj < 5; ++sj) {
        int s = 80 * sg + 16 * sj + 4 * g;
        #pragma unroll
        for (int cj = 0; cj < 4; ++cj) {
            int c = 16 * cj + l15;
            bf16x4 B = *(const bf16x4*)(sm + gts(c, 2 * s));
            #pragma unroll
            for (int mj = 0; mj < 5; ++mj) pacc[mj][cj] = mfma16(P[sj][mj], B, pacc[mj][cj]);
        }
    }
    __syncthreads();   // all GTS reads done -> w2r may overlay

    // ---- ordered cross-wave w2 reduce, float4, layout w2r[c][172] ----
    float* w2r = (float*)(sm + W2R);
    for (int pass = 0; pass < 4; ++pass) {
        if (sg == pass) {
            #pragma unroll
            for (int cj = 0; cj < 4; ++cj) {
                int c = 16 * cj + l15;
                #pragma unroll
                for (int mj = 0; mj < 5; ++mj) {
                    int m = 80 * mg + 16 * mj + 4 * g;
                    float* p = w2r + c * 172 + m;
                    f32x4 v = pacc[mj][cj];
                    if (pass == 0) {
                        *(f32x4*)p = v;
                    } else {
                        f32x4 o = *(const f32x4*)p;
                        o[0] += v[0]; o[1] += v[1]; o[2] += v[2]; o[3] += v[3];
                        *(f32x4*)p = o;
                    }
                }
            }
        }
        __syncthreads();
    }

    // ---- dot partial = sum_m w2^2 ; one atomic per (block, c) ----
    float* fred = (float*)(sm + RED1);
    {
        int c = tid & 63, g8 = wv;          // wave g8 handles m in [20*g8, 20*g8+20)
        float s = 0.f;
        #pragma unroll
        for (int j = 0; j < 5; ++j) {
            f32x4 v = *(const f32x4*)(w2r + c * 172 + 20 * g8 + 4 * j);
            s += v[0] * v[0] + v[1] * v[1] + v[2] * v[2] + v[3] * v[3];
        }
        fred[g8 * 64 + c] = s;
    }
    __syncthreads();
    if (tid < 64) {
        float t = 0.f;
        #pragma unroll
        for (int j = 0; j < 8; ++j) t += fred[j * 64 + tid];
        atomicAdd(out + b * nC + tid, t);
    }
}

extern "C" void kernel_launch(void* const* d_in, const int* in_sizes, int n_in,
                              void* d_out, int out_size, void* d_ws, size_t ws_size,
                              hipStream_t stream) {
    const float* ctx  = (const float*)d_in[0];   // [B,S,H]
    const float* resp = (const float*)d_in[1];   // [B,C,H]
    const float* pos  = (const float*)d_in[2];   // [M,H]
    const int*   mask = (const int*)d_in[3];     // [B,S]
    float* out = (float*)d_out;                  // [B,C]

    (void)hipFuncSetAttribute((const void*)fused,
                              hipFuncAttributeMaxDynamicSharedMemorySize, LDSB);
    (void)hipMemsetAsync(d_out, 0, (size_t)nB * nC * sizeof(float), stream);
    fused<<<nB * 2, 512, LDSB, stream>>>(ctx, resp, pos, mask, out);
}

// Round 13
// 52.546 us; speedup vs baseline: 1.0095x; 1.0095x over previous
//
#include <hip/hip_runtime.h>
#include <hip/hip_bf16.h>

using bf16x8 = __attribute__((ext_vector_type(8))) short;
using bf16x4 = __attribute__((ext_vector_type(4))) short;
using f32x4  = __attribute__((ext_vector_type(4))) float;

namespace {
constexpr int nB = 128, nS = 300, nC = 64, nH = 768, nM = 300;
constexpr int MT  = 160;            // m-tile per block (2 blocks per b)
constexpr int KC  = 32;             // k chunk
constexpr int NKC = nH / KC;        // 24
// LDS (bytes). K-loop: two staging buffers [0, 69632).
// Post-K-loop overlays (staging dead): GTS [0,49152); after PV: W2R [0,44032).
// RED1/RED2 sit in buf1's tail (dead post-K-loop). MASK outside all buffers.
constexpr int BUFSZ    = 34816;     // ctx 20480 + pos 10240 + resp 4096
constexpr int STG_CTX  = 0;         // [320 s][64 B] bf16 chunk, XOR-swizzled
constexpr int STG_POS  = 20480;     // [160 m][64 B]
constexpr int STG_RESP = 30720;     // [64 c][64 B]
constexpr int GTSOF    = 0;         // [64 c][768 B] bf16, XOR (c&15)<<3
constexpr int W2R      = 0;         // [64 c][172 f32] (post-PV only)
constexpr int RED1     = 49152;     // 2560 B (softmax max / final fred)
constexpr int RED2     = 51712;     // 2560 B (softmax sum)
constexpr int MASKOF   = 69632;     // 320 f32 = 1280 B (written at prologue)
constexpr int LDSB     = 70912;
}

// fp32 -> packed 2x bf16 RNE via HIP intrinsic (round-11-proven)
__device__ __forceinline__ unsigned pack2(float a, float b) {
    float2 f2; f2.x = a; f2.y = b;
    __hip_bfloat162 h2 = __float22bfloat162_rn(f2);
    unsigned u;
    __builtin_memcpy(&u, &h2, 4);
    return u;
}
__device__ __forceinline__ uint2 cvt4(float4 v) {
    return make_uint2(pack2(v.x, v.y), pack2(v.z, v.w));
}
// staging swizzle (64B rows): slot XOR (r>>1)&3 -> over 8 consecutive rows the
// bank-quad (4r + slot) mod 8 hits all 8 quads; 16-lane frag reads land
// 2 lanes/quad = conflict-free (verified round 8: 2.56M -> 205K).
__device__ __forceinline__ int swz(int row, int bcol) {
    return row * 64 + (bcol ^ (((row >> 1) & 3) << 4));
}
// GTS swizzle: pitch 768, XOR spreads column accesses across all 32 banks
__device__ __forceinline__ int gts(int c, int bs) {   // bs = 2*s
    return GTSOF + c * 768 + (bs ^ ((c & 15) << 3));
}

__device__ __forceinline__ f32x4 mfma16(bf16x4 a, bf16x4 b, f32x4 c) {
#if __has_builtin(__builtin_amdgcn_mfma_f32_16x16x16bf16_1k)
    return __builtin_amdgcn_mfma_f32_16x16x16bf16_1k(a, b, c, 0, 0, 0);
#else
    asm volatile("v_mfma_f32_16x16x16_bf16 %0, %1, %2, %0"
                 : "+v"(c) : "v"(a), "v"(b));
    return c;
#endif
}

// ---------------------------------------------------------------------------
// One block per (b, m-half). 512 threads = 8 waves: wave = (sg 0..3, mg 0..1).
// K-loop (round-11 schedule, proven): stage(next) -> loads(t+2) -> per-sj frag
//   reads interleaved with the 35-MFMA cluster (setprio(1) wrapped); ONE
//   barrier per chunk, double-buffered.
// Then: GtS write, in-register masked softmax, PV with in-register P A-frags,
//   ordered cross-wave w2 reduce, square-sum, one atomic per (block, c).
// ---------------------------------------------------------------------------
__global__ __launch_bounds__(512, 2) void fused(const float* __restrict__ ctx,
                                                const float* __restrict__ resp,
                                                const float* __restrict__ pos,
                                                const int*  __restrict__ mask,
                                                float* __restrict__ out) {
    extern __shared__ char sm[];
    const int b   = blockIdx.x & 127;
    const int mh  = blockIdx.x >> 7;
    const int m0  = mh * MT;
    const int tid = threadIdx.x;
    const int ln  = tid & 63, wv = tid >> 6;
    const int l15 = ln & 15, g = ln >> 4;
    const int sg  = wv & 3, mg = wv >> 2;

    const float* __restrict__ ctxb  = ctx  + (size_t)b * nS * nH;
    const float* __restrict__ respb = resp + (size_t)b * nC * nH;

    // mask -> LDS once (region outside staging buffers; read post-K-loop,
    // fenced by the K-loop's barriers)
    float* maskS = (float*)(sm + MASKOF);
    if (tid < 320) maskS[tid] = (tid < nS) ? (float)mask[b * nS + tid] : 0.f;

    // hoisted per-thread load pointers (advance by k0 only)
    const float* pcx[5];
    #pragma unroll
    for (int i = 0; i < 5; ++i) {
        int q = i * 512 + tid, r = q >> 3, kq = q & 7;
        int s = (r < nS) ? r : (nS - 1);
        pcx[i] = ctxb + (size_t)s * nH + kq * 4;
    }
    const float* ppx[3];
    #pragma unroll
    for (int i = 0; i < 3; ++i) {
        int q = i * 512 + tid, r = q >> 3, kq = q & 7;
        int m = m0 + r; if (m >= nM) m = nM - 1;
        ppx[i] = pos + (size_t)m * nH + kq * 4;
    }
    const float* prx = respb + (size_t)(tid >> 3) * nH + (tid & 7) * 4;

    f32x4 acc[5][5];    // logits: D[s(sj)][m(mj)] swapped
    f32x4 gacc[5][2];   // G: D[s(sj)][c(cj within mg pair)]
    #pragma unroll
    for (int i = 0; i < 5; ++i) {
        #pragma unroll
        for (int j = 0; j < 5; ++j) acc[i][j] = (f32x4){0.f, 0.f, 0.f, 0.f};
        gacc[i][0] = (f32x4){0.f, 0.f, 0.f, 0.f};
        gacc[i][1] = (f32x4){0.f, 0.f, 0.f, 0.f};
    }

    float4 cR[5], pR[3], rR;
    auto loads = [&](int t) {
        const int k0 = t * KC;
        #pragma unroll
        for (int i = 0; i < 5; ++i) cR[i] = *(const float4*)(pcx[i] + k0);
        #pragma unroll
        for (int i = 0; i < 3; ++i)
            if (i * 512 + tid < 1280) pR[i] = *(const float4*)(ppx[i] + k0);
        rR = *(const float4*)(prx + k0);
    };
    auto stage = [&](char* base) {
        #pragma unroll
        for (int i = 0; i < 5; ++i) {
            int q = i * 512 + tid, r = q >> 3, kq = q & 7;
            *(uint2*)(base + STG_CTX + swz(r, kq * 8)) = cvt4(cR[i]);
        }
        #pragma unroll
        for (int i = 0; i < 3; ++i) {
            int q = i * 512 + tid;
            if (q < 1280) {
                int r = q >> 3, kq = q & 7;
                *(uint2*)(base + STG_POS + swz(r, kq * 8)) = cvt4(pR[i]);
            }
        }
        { int r = tid >> 3, kq = tid & 7;
          *(uint2*)(base + STG_RESP + swz(r, kq * 8)) = cvt4(rR); }
    };

    // prologue: fill buf0 (chunk 0), load chunk 1 into regs
    loads(0);
    stage(sm);
    loads(1);
    __syncthreads();

    int cur = 0;
    for (int t = 0; t < NKC; ++t) {
        char* rbase = sm + cur * BUFSZ;
        if (t + 1 < NKC) stage(sm + (cur ^ 1) * BUFSZ);  // write next chunk
        if (t + 2 < NKC) loads(t + 2);                   // prefetch t+2
        bf16x8 fp[5], fr[2];
        #pragma unroll
        for (int mj = 0; mj < 5; ++mj) {
            int r = 80 * mg + 16 * mj + l15;
            fp[mj] = *(const bf16x8*)(rbase + STG_POS + swz(r, g * 16));
        }
        #pragma unroll
        for (int cj = 0; cj < 2; ++cj) {
            int r = 16 * (2 * mg + cj) + l15;
            fr[cj] = *(const bf16x8*)(rbase + STG_RESP + swz(r, g * 16));
        }
        __builtin_amdgcn_s_setprio(1);   // favor this wave's read+MFMA cluster
        #pragma unroll
        for (int sj = 0; sj < 5; ++sj) {
            int r = 80 * sg + 16 * sj + l15;
            bf16x8 fa = *(const bf16x8*)(rbase + STG_CTX + swz(r, g * 16));
            #pragma unroll
            for (int mj = 0; mj < 5; ++mj)
                acc[sj][mj] = __builtin_amdgcn_mfma_f32_16x16x32_bf16(fa, fp[mj], acc[sj][mj], 0, 0, 0);
            #pragma unroll
            for (int cj = 0; cj < 2; ++cj)
                gacc[sj][cj] = __builtin_amdgcn_mfma_f32_16x16x32_bf16(fa, fr[cj], gacc[sj][cj], 0, 0, 0);
        }
        __builtin_amdgcn_s_setprio(0);
        __syncthreads();   // reads of buf[cur] done; writes of buf[cur^1] visible
        cur ^= 1;
    }

    // ---- GtS[c][s] bf16 (staging dead; overlays buffers) ----
    #pragma unroll
    for (int sj = 0; sj < 5; ++sj)
        #pragma unroll
        for (int cj = 0; cj < 2; ++cj) {
            int c = 16 * (2 * mg + cj) + l15;
            int s = 80 * sg + 16 * sj + 4 * g;
            *(uint2*)(sm + gts(c, 2 * s)) =
                make_uint2(pack2(gacc[sj][cj][0], gacc[sj][cj][1]),
                           pack2(gacc[sj][cj][2], gacc[sj][cj][3]));
        }

    // ---- multiplicative mask (from LDS); pad s rows -> -inf ----
    #pragma unroll
    for (int sj = 0; sj < 5; ++sj)
        #pragma unroll
        for (int r = 0; r < 4; ++r) {
            int s = 80 * sg + 16 * sj + 4 * g + r;
            if (s < nS) {
                float mv = maskS[s];
                #pragma unroll
                for (int mj = 0; mj < 5; ++mj) acc[sj][mj][r] *= mv;
            } else {
                #pragma unroll
                for (int mj = 0; mj < 5; ++mj) acc[sj][mj][r] = -1e30f;
            }
        }

    // ---- softmax over s: in-reg 20-reduce + shfl + LDS across 4 s-waves ----
    float* red1 = (float*)(sm + RED1);
    float* red2 = (float*)(sm + RED2);
    float inv[5];
    {
        float mx[5];
        #pragma unroll
        for (int mj = 0; mj < 5; ++mj) {
            float m = -1e30f;
            #pragma unroll
            for (int sj = 0; sj < 5; ++sj)
                #pragma unroll
                for (int r = 0; r < 4; ++r) m = fmaxf(m, acc[sj][mj][r]);
            m = fmaxf(m, __shfl_xor(m, 16));
            m = fmaxf(m, __shfl_xor(m, 32));
            mx[mj] = m;
        }
        if (ln < 16) {
            #pragma unroll
            for (int mj = 0; mj < 5; ++mj) red1[sg * 160 + 80 * mg + 16 * mj + ln] = mx[mj];
        }
        __syncthreads();   // also publishes GtS writes for PV
        float m4[5];
        #pragma unroll
        for (int mj = 0; mj < 5; ++mj) {
            int idx = 80 * mg + 16 * mj + l15;
            m4[mj] = fmaxf(fmaxf(red1[idx], red1[160 + idx]),
                           fmaxf(red1[320 + idx], red1[480 + idx]));
        }
        float sum[5];
        #pragma unroll
        for (int mj = 0; mj < 5; ++mj) {
            float s = 0.f;
            #pragma unroll
            for (int sj = 0; sj < 5; ++sj)
                #pragma unroll
                for (int r = 0; r < 4; ++r) {
                    float e = __expf(acc[sj][mj][r] - m4[mj]);
                    acc[sj][mj][r] = e;
                    s += e;
                }
            s += __shfl_xor(s, 16);
            s += __shfl_xor(s, 32);
            sum[mj] = s;
        }
        if (ln < 16) {
            #pragma unroll
            for (int mj = 0; mj < 5; ++mj) red2[sg * 160 + 80 * mg + 16 * mj + ln] = sum[mj];
        }
        __syncthreads();
        #pragma unroll
        for (int mj = 0; mj < 5; ++mj) {
            int idx = 80 * mg + 16 * mj + l15;
            float tt = red2[idx] + red2[160 + idx] + red2[320 + idx] + red2[480 + idx];
            int mglob = m0 + 80 * mg + 16 * mj + l15;
            inv[mj] = (mglob < nM) ? (1.0f / tt) : 0.0f;   // pad m rows -> P = 0
        }
    }

    // ---- P in-register (16x16x16 A-layout: k = 4*g + j matches swapped C) ----
    union PU { uint2 u; bf16x4 v; };
    bf16x4 P[5][5];
    #pragma unroll
    for (int sj = 0; sj < 5; ++sj)
        #pragma unroll
        for (int mj = 0; mj < 5; ++mj) {
            PU pu;
            pu.u = make_uint2(pack2(acc[sj][mj][0] * inv[mj], acc[sj][mj][1] * inv[mj]),
                              pack2(acc[sj][mj][2] * inv[mj], acc[sj][mj][3] * inv[mj]));
            P[sj][mj] = pu.v;
        }

    // ---- PV: partial w2 over this wave's s-range ----
    f32x4 pacc[5][4];
    #pragma unroll
    for (int mj = 0; mj < 5; ++mj)
        #pragma unroll
        for (int cj = 0; cj < 4; ++cj) pacc[mj][cj] = (f32x4){0.f, 0.f, 0.f, 0.f};
    #pragma unroll
    for (int sj = 0; sj < 5; ++sj) {
        int s = 80 * sg + 16 * sj + 4 * g;
        #pragma unroll
        for (int cj = 0; cj < 4; ++cj) {
            int c = 16 * cj + l15;
            bf16x4 B = *(const bf16x4*)(sm + gts(c, 2 * s));
            #pragma unroll
            for (int mj = 0; mj < 5; ++mj) pacc[mj][cj] = mfma16(P[sj][mj], B, pacc[mj][cj]);
        }
    }
    __syncthreads();   // all GTS reads done -> w2r may overlay

    // ---- ordered cross-wave w2 reduce, float4, layout w2r[c][172] ----
    float* w2r = (float*)(sm + W2R);
    for (int pass = 0; pass < 4; ++pass) {
        if (sg == pass) {
            #pragma unroll
            for (int cj = 0; cj < 4; ++cj) {
                int c = 16 * cj + l15;
                #pragma unroll
                for (int mj = 0; mj < 5; ++mj) {
                    int m = 80 * mg + 16 * mj + 4 * g;
                    float* p = w2r + c * 172 + m;
                    f32x4 v = pacc[mj][cj];
                    if (pass == 0) {
                        *(f32x4*)p = v;
                    } else {
                        f32x4 o = *(const f32x4*)p;
                        o[0] += v[0]; o[1] += v[1]; o[2] += v[2]; o[3] += v[3];
                        *(f32x4*)p = o;
                    }
                }
            }
        }
        __syncthreads();
    }

    // ---- dot partial = sum_m w2^2 ; one atomic per (block, c) ----
    float* fred = (float*)(sm + RED1);
    {
        int c = tid & 63, g8 = wv;          // wave g8 handles m in [20*g8, 20*g8+20)
        float s = 0.f;
        #pragma unroll
        for (int j = 0; j < 5; ++j) {
            f32x4 v = *(const f32x4*)(w2r + c * 172 + 20 * g8 + 4 * j);
            s += v[0] * v[0] + v[1] * v[1] + v[2] * v[2] + v[3] * v[3];
        }
        fred[g8 * 64 + c] = s;
    }
    __syncthreads();
    if (tid < 64) {
        float t = 0.f;
        #pragma unroll
        for (int j = 0; j < 8; ++j) t += fred[j * 64 + tid];
        atomicAdd(out + b * nC + tid, t);
    }
}

extern "C" void kernel_launch(void* const* d_in, const int* in_sizes, int n_in,
                              void* d_out, int out_size, void* d_ws, size_t ws_size,
                              hipStream_t stream) {
    const float* ctx  = (const float*)d_in[0];   // [B,S,H]
    const float* resp = (const float*)d_in[1];   // [B,C,H]
    const float* pos  = (const float*)d_in[2];   // [M,H]
    const int*   mask = (const int*)d_in[3];     // [B,S]
    float* out = (float*)d_out;                  // [B,C]

    (void)hipFuncSetAttribute((const void*)fused,
                              hipFuncAttributeMaxDynamicSharedMemorySize, LDSB);
    (void)hipMemsetAsync(d_out, 0, (size_t)nB * nC * sizeof(float), stream);
    fused<<<nB * 2, 512, LDSB, stream>>>(ctx, resp, pos, mask, out);
}

// Round 14
// 51.412 us; speedup vs baseline: 1.0318x; 1.0221x over previous
//
#include <hip/hip_runtime.h>
#include <hip/hip_bf16.h>

using bf16x8 = __attribute__((ext_vector_type(8))) short;
using bf16x4 = __attribute__((ext_vector_type(4))) short;
using f32x4  = __attribute__((ext_vector_type(4))) float;

namespace {
constexpr int nB = 128, nS = 300, nC = 64, nH = 768, nM = 300;
constexpr int MT  = 160;            // m-tile per block (2 blocks per b)
constexpr int KC  = 32;             // k chunk
constexpr int NKC = nH / KC;        // 24
// LDS (bytes). K-loop: two staging buffers [0, 69632).
// Post-K-loop overlays (staging dead): GTS [0,49152); after PV: W2R [0,44032).
// RED1/RED2 sit in buf1's tail (dead post-K-loop).
constexpr int BUFSZ    = 34816;     // ctx 20480 + pos 10240 + resp 4096
constexpr int STG_CTX  = 0;         // [320 s][64 B] bf16 chunk, XOR-swizzled
constexpr int STG_POS  = 20480;     // [160 m][64 B]
constexpr int STG_RESP = 30720;     // [64 c][64 B]
constexpr int GTSOF    = 0;         // [64 c][768 B] bf16, XOR (c&15)<<3
constexpr int W2R      = 0;         // [64 c][172 f32] (post-PV only)
constexpr int RED1     = 49152;     // 2560 B (softmax max / final fred)
constexpr int RED2     = 51712;     // 2560 B (softmax sum)
constexpr int LDSB     = 69632;
}

// fp32 -> packed 2x bf16 RNE via the HIP intrinsic (round-11-proven: cut
// VALUBusy 18 -> 14%). memcpy extraction avoids the bit_cast compile error.
__device__ __forceinline__ unsigned pack2(float a, float b) {
    float2 f2; f2.x = a; f2.y = b;
    __hip_bfloat162 h2 = __float22bfloat162_rn(f2);
    unsigned u;
    __builtin_memcpy(&u, &h2, 4);
    return u;
}
__device__ __forceinline__ uint2 cvt4(float4 v) {
    return make_uint2(pack2(v.x, v.y), pack2(v.z, v.w));
}
// staging swizzle (64B rows): slot XOR (r>>1)&3 -> over 8 consecutive rows the
// bank-quad (4r + slot) mod 8 hits all 8 quads; 16-lane frag reads land
// 2 lanes/quad = conflict-free (verified round 8: 2.56M -> 205K).
__device__ __forceinline__ int swz(int row, int bcol) {
    return row * 64 + (bcol ^ (((row >> 1) & 3) << 4));
}
// GTS swizzle: pitch 768, XOR spreads the 16 8B-slots of a column access
// across all 32 banks (balanced for both write and PV read)
__device__ __forceinline__ int gts(int c, int bs) {   // bs = 2*s
    return GTSOF + c * 768 + (bs ^ ((c & 15) << 3));
}

__device__ __forceinline__ f32x4 mfma16(bf16x4 a, bf16x4 b, f32x4 c) {
#if __has_builtin(__builtin_amdgcn_mfma_f32_16x16x16bf16_1k)
    return __builtin_amdgcn_mfma_f32_16x16x16bf16_1k(a, b, c, 0, 0, 0);
#else
    asm volatile("v_mfma_f32_16x16x16_bf16 %0, %1, %2, %0"
                 : "+v"(c) : "v"(a), "v"(b));
    return c;
#endif
}

// ---------------------------------------------------------------------------
// One block per (b, m-half). 512 threads = 8 waves: wave = (sg 0..3, mg 0..1).
// K-loop (round-8/11 schedule, best measured): stage(next) -> loads(t+2) ->
//   per-sj frag reads interleaved with the 35-MFMA cluster; ONE barrier per
//   chunk, double-buffered.
// Then: GtS write, in-register masked softmax, PV with in-register P A-frags,
//   ordered cross-wave w2 reduce, square-sum, one atomic per (block, c).
// ---------------------------------------------------------------------------
__global__ __launch_bounds__(512, 2) void fused(const float* __restrict__ ctx,
                                                const float* __restrict__ resp,
                                                const float* __restrict__ pos,
                                                const int*  __restrict__ mask,
                                                float* __restrict__ out) {
    extern __shared__ char sm[];
    const int b   = blockIdx.x & 127;
    const int mh  = blockIdx.x >> 7;
    const int m0  = mh * MT;
    const int tid = threadIdx.x;
    const int ln  = tid & 63, wv = tid >> 6;
    const int l15 = ln & 15, g = ln >> 4;
    const int sg  = wv & 3, mg = wv >> 2;

    const float* __restrict__ ctxb  = ctx  + (size_t)b * nS * nH;
    const float* __restrict__ respb = resp + (size_t)b * nC * nH;

    // hoisted per-thread load pointers (advance by k0 only)
    const float* pcx[5];
    #pragma unroll
    for (int i = 0; i < 5; ++i) {
        int q = i * 512 + tid, r = q >> 3, kq = q & 7;
        int s = (r < nS) ? r : (nS - 1);
        pcx[i] = ctxb + (size_t)s * nH + kq * 4;
    }
    const float* ppx[3];
    #pragma unroll
    for (int i = 0; i < 3; ++i) {
        int q = i * 512 + tid, r = q >> 3, kq = q & 7;
        int m = m0 + r; if (m >= nM) m = nM - 1;
        ppx[i] = pos + (size_t)m * nH + kq * 4;
    }
    const float* prx = respb + (size_t)(tid >> 3) * nH + (tid & 7) * 4;

    f32x4 acc[5][5];    // logits: D[s(sj)][m(mj)] swapped
    f32x4 gacc[5][2];   // G: D[s(sj)][c(cj within mg pair)]
    #pragma unroll
    for (int i = 0; i < 5; ++i) {
        #pragma unroll
        for (int j = 0; j < 5; ++j) acc[i][j] = (f32x4){0.f, 0.f, 0.f, 0.f};
        gacc[i][0] = (f32x4){0.f, 0.f, 0.f, 0.f};
        gacc[i][1] = (f32x4){0.f, 0.f, 0.f, 0.f};
    }

    float4 cR[5], pR[3], rR;
    auto loads = [&](int t) {
        const int k0 = t * KC;
        #pragma unroll
        for (int i = 0; i < 5; ++i) cR[i] = *(const float4*)(pcx[i] + k0);
        #pragma unroll
        for (int i = 0; i < 3; ++i)
            if (i * 512 + tid < 1280) pR[i] = *(const float4*)(ppx[i] + k0);
        rR = *(const float4*)(prx + k0);
    };
    auto stage = [&](char* base) {
        #pragma unroll
        for (int i = 0; i < 5; ++i) {
            int q = i * 512 + tid, r = q >> 3, kq = q & 7;
            *(uint2*)(base + STG_CTX + swz(r, kq * 8)) = cvt4(cR[i]);
        }
        #pragma unroll
        for (int i = 0; i < 3; ++i) {
            int q = i * 512 + tid;
            if (q < 1280) {
                int r = q >> 3, kq = q & 7;
                *(uint2*)(base + STG_POS + swz(r, kq * 8)) = cvt4(pR[i]);
            }
        }
        { int r = tid >> 3, kq = tid & 7;
          *(uint2*)(base + STG_RESP + swz(r, kq * 8)) = cvt4(rR); }
    };

    // prologue: fill buf0 (chunk 0), load chunk 1 into regs
    loads(0);
    stage(sm);
    loads(1);
    __syncthreads();

    int cur = 0;
    for (int t = 0; t < NKC; ++t) {
        char* rbase = sm + cur * BUFSZ;
        if (t + 1 < NKC) stage(sm + (cur ^ 1) * BUFSZ);  // write next chunk
        if (t + 2 < NKC) loads(t + 2);                   // prefetch t+2
        bf16x8 fp[5], fr[2];
        #pragma unroll
        for (int mj = 0; mj < 5; ++mj) {
            int r = 80 * mg + 16 * mj + l15;
            fp[mj] = *(const bf16x8*)(rbase + STG_POS + swz(r, g * 16));
        }
        #pragma unroll
        for (int cj = 0; cj < 2; ++cj) {
            int r = 16 * (2 * mg + cj) + l15;
            fr[cj] = *(const bf16x8*)(rbase + STG_RESP + swz(r, g * 16));
        }
        #pragma unroll
        for (int sj = 0; sj < 5; ++sj) {
            int r = 80 * sg + 16 * sj + l15;
            bf16x8 fa = *(const bf16x8*)(rbase + STG_CTX + swz(r, g * 16));
            #pragma unroll
            for (int mj = 0; mj < 5; ++mj)
                acc[sj][mj] = __builtin_amdgcn_mfma_f32_16x16x32_bf16(fa, fp[mj], acc[sj][mj], 0, 0, 0);
            #pragma unroll
            for (int cj = 0; cj < 2; ++cj)
                gacc[sj][cj] = __builtin_amdgcn_mfma_f32_16x16x32_bf16(fa, fr[cj], gacc[sj][cj], 0, 0, 0);
        }
        __syncthreads();   // reads of buf[cur] done; writes of buf[cur^1] visible
        cur ^= 1;
    }

    // ---- GtS[c][s] bf16 (staging dead; overlays buffers) ----
    #pragma unroll
    for (int sj = 0; sj < 5; ++sj)
        #pragma unroll
        for (int cj = 0; cj < 2; ++cj) {
            int c = 16 * (2 * mg + cj) + l15;
            int s = 80 * sg + 16 * sj + 4 * g;
            *(uint2*)(sm + gts(c, 2 * s)) =
                make_uint2(pack2(gacc[sj][cj][0], gacc[sj][cj][1]),
                           pack2(gacc[sj][cj][2], gacc[sj][cj][3]));
        }

    // ---- multiplicative mask; pad s rows -> -inf ----
    #pragma unroll
    for (int sj = 0; sj < 5; ++sj)
        #pragma unroll
        for (int r = 0; r < 4; ++r) {
            int s = 80 * sg + 16 * sj + 4 * g + r;
            if (s < nS) {
                float mv = (float)mask[b * nS + s];
                #pragma unroll
                for (int mj = 0; mj < 5; ++mj) acc[sj][mj][r] *= mv;
            } else {
                #pragma unroll
                for (int mj = 0; mj < 5; ++mj) acc[sj][mj][r] = -1e30f;
            }
        }

    // ---- softmax over s: in-reg 20-reduce + shfl + LDS across 4 s-waves ----
    float* red1 = (float*)(sm + RED1);
    float* red2 = (float*)(sm + RED2);
    float inv[5];
    {
        float mx[5];
        #pragma unroll
        for (int mj = 0; mj < 5; ++mj) {
            float m = -1e30f;
            #pragma unroll
            for (int sj = 0; sj < 5; ++sj)
                #pragma unroll
                for (int r = 0; r < 4; ++r) m = fmaxf(m, acc[sj][mj][r]);
            m = fmaxf(m, __shfl_xor(m, 16));
            m = fmaxf(m, __shfl_xor(m, 32));
            mx[mj] = m;
        }
        if (ln < 16) {
            #pragma unroll
            for (int mj = 0; mj < 5; ++mj) red1[sg * 160 + 80 * mg + 16 * mj + ln] = mx[mj];
        }
        __syncthreads();   // also publishes GtS writes for PV
        float m4[5];
        #pragma unroll
        for (int mj = 0; mj < 5; ++mj) {
            int idx = 80 * mg + 16 * mj + l15;
            m4[mj] = fmaxf(fmaxf(red1[idx], red1[160 + idx]),
                           fmaxf(red1[320 + idx], red1[480 + idx]));
        }
        float sum[5];
        #pragma unroll
        for (int mj = 0; mj < 5; ++mj) {
            float s = 0.f;
            #pragma unroll
            for (int sj = 0; sj < 5; ++sj)
                #pragma unroll
                for (int r = 0; r < 4; ++r) {
                    float e = __expf(acc[sj][mj][r] - m4[mj]);
                    acc[sj][mj][r] = e;
                    s += e;
                }
            s += __shfl_xor(s, 16);
            s += __shfl_xor(s, 32);
            sum[mj] = s;
        }
        if (ln < 16) {
            #pragma unroll
            for (int mj = 0; mj < 5; ++mj) red2[sg * 160 + 80 * mg + 16 * mj + ln] = sum[mj];
        }
        __syncthreads();
        #pragma unroll
        for (int mj = 0; mj < 5; ++mj) {
            int idx = 80 * mg + 16 * mj + l15;
            float tt = red2[idx] + red2[160 + idx] + red2[320 + idx] + red2[480 + idx];
            int mglob = m0 + 80 * mg + 16 * mj + l15;
            inv[mj] = (mglob < nM) ? (1.0f / tt) : 0.0f;   // pad m rows -> P = 0
        }
    }

    // ---- P in-register (16x16x16 A-layout: k = 4*g + j matches swapped C) ----
    union PU { uint2 u; bf16x4 v; };
    bf16x4 P[5][5];
    #pragma unroll
    for (int sj = 0; sj < 5; ++sj)
        #pragma unroll
        for (int mj = 0; mj < 5; ++mj) {
            PU pu;
            pu.u = make_uint2(pack2(acc[sj][mj][0] * inv[mj], acc[sj][mj][1] * inv[mj]),
                              pack2(acc[sj][mj][2] * inv[mj], acc[sj][mj][3] * inv[mj]));
            P[sj][mj] = pu.v;
        }

    // ---- PV: partial w2 over this wave's s-range ----
    f32x4 pacc[5][4];
    #pragma unroll
    for (int mj = 0; mj < 5; ++mj)
        #pragma unroll
        for (int cj = 0; cj < 4; ++cj) pacc[mj][cj] = (f32x4){0.f, 0.f, 0.f, 0.f};
    #pragma unroll
    for (int sj = 0; sj < 5; ++sj) {
        int s = 80 * sg + 16 * sj + 4 * g;
        #pragma unroll
        for (int cj = 0; cj < 4; ++cj) {
            int c = 16 * cj + l15;
            bf16x4 B = *(const bf16x4*)(sm + gts(c, 2 * s));
            #pragma unroll
            for (int mj = 0; mj < 5; ++mj) pacc[mj][cj] = mfma16(P[sj][mj], B, pacc[mj][cj]);
        }
    }
    __syncthreads();   // all GTS reads done -> w2r may overlay

    // ---- ordered cross-wave w2 reduce, float4, layout w2r[c][172] ----
    float* w2r = (float*)(sm + W2R);
    for (int pass = 0; pass < 4; ++pass) {
        if (sg == pass) {
            #pragma unroll
            for (int cj = 0; cj < 4; ++cj) {
                int c = 16 * cj + l15;
                #pragma unroll
                for (int mj = 0; mj < 5; ++mj) {
                    int m = 80 * mg + 16 * mj + 4 * g;
                    float* p = w2r + c * 172 + m;
                    f32x4 v = pacc[mj][cj];
                    if (pass == 0) {
                        *(f32x4*)p = v;
                    } else {
                        f32x4 o = *(const f32x4*)p;
                        o[0] += v[0]; o[1] += v[1]; o[2] += v[2]; o[3] += v[3];
                        *(f32x4*)p = o;
                    }
                }
            }
        }
        __syncthreads();
    }

    // ---- dot partial = sum_m w2^2 ; one atomic per (block, c) ----
    float* fred = (float*)(sm + RED1);
    {
        int c = tid & 63, g8 = wv;          // wave g8 handles m in [20*g8, 20*g8+20)
        float s = 0.f;
        #pragma unroll
        for (int j = 0; j < 5; ++j) {
            f32x4 v = *(const f32x4*)(w2r + c * 172 + 20 * g8 + 4 * j);
            s += v[0] * v[0] + v[1] * v[1] + v[2] * v[2] + v[3] * v[3];
        }
        fred[g8 * 64 + c] = s;
    }
    __syncthreads();
    if (tid < 64) {
        float t = 0.f;
        #pragma unroll
        for (int j = 0; j < 8; ++j) t += fred[j * 64 + tid];
        atomicAdd(out + b * nC + tid, t);
    }
}

extern "C" void kernel_launch(void* const* d_in, const int* in_sizes, int n_in,
                              void* d_out, int out_size, void* d_ws, size_t ws_size,
                              hipStream_t stream) {
    const float* ctx  = (const float*)d_in[0];   // [B,S,H]
    const float* resp = (const float*)d_in[1];   // [B,C,H]
    const float* pos  = (const float*)d_in[2];   // [M,H]
    const int*   mask = (const int*)d_in[3];     // [B,S]
    float* out = (float*)d_out;                  // [B,C]

    (void)hipFuncSetAttribute((const void*)fused,
                              hipFuncAttributeMaxDynamicSharedMemorySize, LDSB);
    (void)hipMemsetAsync(d_out, 0, (size_t)nB * nC * sizeof(float), stream);
    fused<<<nB * 2, 512, LDSB, stream>>>(ctx, resp, pos, mask, out);
}

// Round 15
// 50.989 us; speedup vs baseline: 1.0404x; 1.0083x over previous
//
#include <hip/hip_runtime.h>
#include <hip/hip_bf16.h>

using bf16x8 = __attribute__((ext_vector_type(8))) short;
using bf16x4 = __attribute__((ext_vector_type(4))) short;
using f32x4  = __attribute__((ext_vector_type(4))) float;

namespace {
constexpr int nB = 128, nS = 300, nC = 64, nH = 768, nM = 300;
constexpr int MT  = 160;            // m-tile per block (2 blocks per b)
constexpr int KC  = 32;             // k chunk
constexpr int NKC = nH / KC;        // 24
// LDS (bytes). K-loop: two staging buffers [0, 69632).
// Post-K-loop overlays (staging dead): GTS [0,49152); after PV: W2RA/W2RB
// [0,88064). RED1/RED2 live past all of it.
constexpr int BUFSZ    = 34816;     // ctx 20480 + pos 10240 + resp 4096
constexpr int STG_CTX  = 0;         // [320 s][64 B] bf16 chunk, XOR-swizzled
constexpr int STG_POS  = 20480;     // [160 m][64 B]
constexpr int STG_RESP = 30720;     // [64 c][64 B]
constexpr int GTSOF    = 0;         // [64 c][768 B] bf16, XOR (c&15)<<3
constexpr int W2RA     = 0;         // [64 c][172 f32] = 44032 (post-PV only)
constexpr int W2RB     = 44032;     // [64 c][172 f32] = 44032 (post-PV only)
constexpr int RED1     = 88064;     // 2560 B (softmax max / final fred)
constexpr int RED2     = 90624;     // 2560 B (softmax sum)
constexpr int LDSB     = 93184;
}

// fp32 -> packed 2x bf16 RNE via the HIP intrinsic (round-11-proven: cut
// VALUBusy 18 -> 14%). memcpy extraction avoids the bit_cast compile error.
__device__ __forceinline__ unsigned pack2(float a, float b) {
    float2 f2; f2.x = a; f2.y = b;
    __hip_bfloat162 h2 = __float22bfloat162_rn(f2);
    unsigned u;
    __builtin_memcpy(&u, &h2, 4);
    return u;
}
__device__ __forceinline__ uint2 cvt4(float4 v) {
    return make_uint2(pack2(v.x, v.y), pack2(v.z, v.w));
}
// staging swizzle (64B rows): slot XOR (r>>1)&3 -> over 8 consecutive rows the
// bank-quad (4r + slot) mod 8 hits all 8 quads; 16-lane frag reads land
// 2 lanes/quad = conflict-free (verified round 8: 2.56M -> 205K).
__device__ __forceinline__ int swz(int row, int bcol) {
    return row * 64 + (bcol ^ (((row >> 1) & 3) << 4));
}
// GTS swizzle: pitch 768, XOR spreads the 16 8B-slots of a column access
// across all 32 banks (balanced for both write and PV read)
__device__ __forceinline__ int gts(int c, int bs) {   // bs = 2*s
    return GTSOF + c * 768 + (bs ^ ((c & 15) << 3));
}

__device__ __forceinline__ f32x4 mfma16(bf16x4 a, bf16x4 b, f32x4 c) {
#if __has_builtin(__builtin_amdgcn_mfma_f32_16x16x16bf16_1k)
    return __builtin_amdgcn_mfma_f32_16x16x16bf16_1k(a, b, c, 0, 0, 0);
#else
    asm volatile("v_mfma_f32_16x16x16_bf16 %0, %1, %2, %0"
                 : "+v"(c) : "v"(a), "v"(b));
    return c;
#endif
}

// ---------------------------------------------------------------------------
// One block per (b, m-half). 512 threads = 8 waves: wave = (sg 0..3, mg 0..1).
// K-loop (round-8/11 schedule, best measured): stage(next) -> loads(t+2) ->
//   per-sj frag reads interleaved with the 35-MFMA cluster; ONE barrier per
//   chunk, double-buffered.
// Then: GtS write, in-register masked softmax, PV with in-register P A-frags,
//   TWO-REGION cross-wave w2 reduce (A: sg0->sg1, B: sg2->sg3; 2 barrier
//   periods, 4/8 waves active each), square-sum of (A+B), one atomic/(block,c).
// ---------------------------------------------------------------------------
__global__ __launch_bounds__(512, 2) void fused(const float* __restrict__ ctx,
                                                const float* __restrict__ resp,
                                                const float* __restrict__ pos,
                                                const int*  __restrict__ mask,
                                                float* __restrict__ out) {
    extern __shared__ char sm[];
    const int b   = blockIdx.x & 127;
    const int mh  = blockIdx.x >> 7;
    const int m0  = mh * MT;
    const int tid = threadIdx.x;
    const int ln  = tid & 63, wv = tid >> 6;
    const int l15 = ln & 15, g = ln >> 4;
    const int sg  = wv & 3, mg = wv >> 2;

    const float* __restrict__ ctxb  = ctx  + (size_t)b * nS * nH;
    const float* __restrict__ respb = resp + (size_t)b * nC * nH;

    // hoisted per-thread load pointers (advance by k0 only)
    const float* pcx[5];
    #pragma unroll
    for (int i = 0; i < 5; ++i) {
        int q = i * 512 + tid, r = q >> 3, kq = q & 7;
        int s = (r < nS) ? r : (nS - 1);
        pcx[i] = ctxb + (size_t)s * nH + kq * 4;
    }
    const float* ppx[3];
    #pragma unroll
    for (int i = 0; i < 3; ++i) {
        int q = i * 512 + tid, r = q >> 3, kq = q & 7;
        int m = m0 + r; if (m >= nM) m = nM - 1;
        ppx[i] = pos + (size_t)m * nH + kq * 4;
    }
    const float* prx = respb + (size_t)(tid >> 3) * nH + (tid & 7) * 4;

    f32x4 acc[5][5];    // logits: D[s(sj)][m(mj)] swapped
    f32x4 gacc[5][2];   // G: D[s(sj)][c(cj within mg pair)]
    #pragma unroll
    for (int i = 0; i < 5; ++i) {
        #pragma unroll
        for (int j = 0; j < 5; ++j) acc[i][j] = (f32x4){0.f, 0.f, 0.f, 0.f};
        gacc[i][0] = (f32x4){0.f, 0.f, 0.f, 0.f};
        gacc[i][1] = (f32x4){0.f, 0.f, 0.f, 0.f};
    }

    float4 cR[5], pR[3], rR;
    auto loads = [&](int t) {
        const int k0 = t * KC;
        #pragma unroll
        for (int i = 0; i < 5; ++i) cR[i] = *(const float4*)(pcx[i] + k0);
        #pragma unroll
        for (int i = 0; i < 3; ++i)
            if (i * 512 + tid < 1280) pR[i] = *(const float4*)(ppx[i] + k0);
        rR = *(const float4*)(prx + k0);
    };
    auto stage = [&](char* base) {
        #pragma unroll
        for (int i = 0; i < 5; ++i) {
            int q = i * 512 + tid, r = q >> 3, kq = q & 7;
            *(uint2*)(base + STG_CTX + swz(r, kq * 8)) = cvt4(cR[i]);
        }
        #pragma unroll
        for (int i = 0; i < 3; ++i) {
            int q = i * 512 + tid;
            if (q < 1280) {
                int r = q >> 3, kq = q & 7;
                *(uint2*)(base + STG_POS + swz(r, kq * 8)) = cvt4(pR[i]);
            }
        }
        { int r = tid >> 3, kq = tid & 7;
          *(uint2*)(base + STG_RESP + swz(r, kq * 8)) = cvt4(rR); }
    };

    // prologue: fill buf0 (chunk 0), load chunk 1 into regs
    loads(0);
    stage(sm);
    loads(1);
    __syncthreads();

    int cur = 0;
    for (int t = 0; t < NKC; ++t) {
        char* rbase = sm + cur * BUFSZ;
        if (t + 1 < NKC) stage(sm + (cur ^ 1) * BUFSZ);  // write next chunk
        if (t + 2 < NKC) loads(t + 2);                   // prefetch t+2
        bf16x8 fp[5], fr[2];
        #pragma unroll
        for (int mj = 0; mj < 5; ++mj) {
            int r = 80 * mg + 16 * mj + l15;
            fp[mj] = *(const bf16x8*)(rbase + STG_POS + swz(r, g * 16));
        }
        #pragma unroll
        for (int cj = 0; cj < 2; ++cj) {
            int r = 16 * (2 * mg + cj) + l15;
            fr[cj] = *(const bf16x8*)(rbase + STG_RESP + swz(r, g * 16));
        }
        #pragma unroll
        for (int sj = 0; sj < 5; ++sj) {
            int r = 80 * sg + 16 * sj + l15;
            bf16x8 fa = *(const bf16x8*)(rbase + STG_CTX + swz(r, g * 16));
            #pragma unroll
            for (int mj = 0; mj < 5; ++mj)
                acc[sj][mj] = __builtin_amdgcn_mfma_f32_16x16x32_bf16(fa, fp[mj], acc[sj][mj], 0, 0, 0);
            #pragma unroll
            for (int cj = 0; cj < 2; ++cj)
                gacc[sj][cj] = __builtin_amdgcn_mfma_f32_16x16x32_bf16(fa, fr[cj], gacc[sj][cj], 0, 0, 0);
        }
        __syncthreads();   // reads of buf[cur] done; writes of buf[cur^1] visible
        cur ^= 1;
    }

    // ---- GtS[c][s] bf16 (staging dead; overlays buffers) ----
    #pragma unroll
    for (int sj = 0; sj < 5; ++sj)
        #pragma unroll
        for (int cj = 0; cj < 2; ++cj) {
            int c = 16 * (2 * mg + cj) + l15;
            int s = 80 * sg + 16 * sj + 4 * g;
            *(uint2*)(sm + gts(c, 2 * s)) =
                make_uint2(pack2(gacc[sj][cj][0], gacc[sj][cj][1]),
                           pack2(gacc[sj][cj][2], gacc[sj][cj][3]));
        }

    // ---- multiplicative mask; pad s rows -> -inf ----
    #pragma unroll
    for (int sj = 0; sj < 5; ++sj)
        #pragma unroll
        for (int r = 0; r < 4; ++r) {
            int s = 80 * sg + 16 * sj + 4 * g + r;
            if (s < nS) {
                float mv = (float)mask[b * nS + s];
                #pragma unroll
                for (int mj = 0; mj < 5; ++mj) acc[sj][mj][r] *= mv;
            } else {
                #pragma unroll
                for (int mj = 0; mj < 5; ++mj) acc[sj][mj][r] = -1e30f;
            }
        }

    // ---- softmax over s: in-reg 20-reduce + shfl + LDS across 4 s-waves ----
    float* red1 = (float*)(sm + RED1);
    float* red2 = (float*)(sm + RED2);
    float inv[5];
    {
        float mx[5];
        #pragma unroll
        for (int mj = 0; mj < 5; ++mj) {
            float m = -1e30f;
            #pragma unroll
            for (int sj = 0; sj < 5; ++sj)
                #pragma unroll
                for (int r = 0; r < 4; ++r) m = fmaxf(m, acc[sj][mj][r]);
            m = fmaxf(m, __shfl_xor(m, 16));
            m = fmaxf(m, __shfl_xor(m, 32));
            mx[mj] = m;
        }
        if (ln < 16) {
            #pragma unroll
            for (int mj = 0; mj < 5; ++mj) red1[sg * 160 + 80 * mg + 16 * mj + ln] = mx[mj];
        }
        __syncthreads();   // also publishes GtS writes for PV
        float m4[5];
        #pragma unroll
        for (int mj = 0; mj < 5; ++mj) {
            int idx = 80 * mg + 16 * mj + l15;
            m4[mj] = fmaxf(fmaxf(red1[idx], red1[160 + idx]),
                           fmaxf(red1[320 + idx], red1[480 + idx]));
        }
        float sum[5];
        #pragma unroll
        for (int mj = 0; mj < 5; ++mj) {
            float s = 0.f;
            #pragma unroll
            for (int sj = 0; sj < 5; ++sj)
                #pragma unroll
                for (int r = 0; r < 4; ++r) {
                    float e = __expf(acc[sj][mj][r] - m4[mj]);
                    acc[sj][mj][r] = e;
                    s += e;
                }
            s += __shfl_xor(s, 16);
            s += __shfl_xor(s, 32);
            sum[mj] = s;
        }
        if (ln < 16) {
            #pragma unroll
            for (int mj = 0; mj < 5; ++mj) red2[sg * 160 + 80 * mg + 16 * mj + ln] = sum[mj];
        }
        __syncthreads();
        #pragma unroll
        for (int mj = 0; mj < 5; ++mj) {
            int idx = 80 * mg + 16 * mj + l15;
            float tt = red2[idx] + red2[160 + idx] + red2[320 + idx] + red2[480 + idx];
            int mglob = m0 + 80 * mg + 16 * mj + l15;
            inv[mj] = (mglob < nM) ? (1.0f / tt) : 0.0f;   // pad m rows -> P = 0
        }
    }

    // ---- P in-register (16x16x16 A-layout: k = 4*g + j matches swapped C) ----
    union PU { uint2 u; bf16x4 v; };
    bf16x4 P[5][5];
    #pragma unroll
    for (int sj = 0; sj < 5; ++sj)
        #pragma unroll
        for (int mj = 0; mj < 5; ++mj) {
            PU pu;
            pu.u = make_uint2(pack2(acc[sj][mj][0] * inv[mj], acc[sj][mj][1] * inv[mj]),
                              pack2(acc[sj][mj][2] * inv[mj], acc[sj][mj][3] * inv[mj]));
            P[sj][mj] = pu.v;
        }

    // ---- PV: partial w2 over this wave's s-range ----
    f32x4 pacc[5][4];
    #pragma unroll
    for (int mj = 0; mj < 5; ++mj)
        #pragma unroll
        for (int cj = 0; cj < 4; ++cj) pacc[mj][cj] = (f32x4){0.f, 0.f, 0.f, 0.f};
    #pragma unroll
    for (int sj = 0; sj < 5; ++sj) {
        int s = 80 * sg + 16 * sj + 4 * g;
        #pragma unroll
        for (int cj = 0; cj < 4; ++cj) {
            int c = 16 * cj + l15;
            bf16x4 B = *(const bf16x4*)(sm + gts(c, 2 * s));
            #pragma unroll
            for (int mj = 0; mj < 5; ++mj) pacc[mj][cj] = mfma16(P[sj][mj], B, pacc[mj][cj]);
        }
    }
    __syncthreads();   // all GTS reads done -> w2 regions may overlay

    // ---- two-region cross-wave w2 reduce (A: sg0 then sg1; B: sg2 then sg3) ----
    float* w2rA = (float*)(sm + W2RA);
    float* w2rB = (float*)(sm + W2RB);
    {
        float* dst = (sg & 2) ? w2rB : w2rA;
        if ((sg & 1) == 0) {   // sg 0 / sg 2: initialize
            #pragma unroll
            for (int cj = 0; cj < 4; ++cj) {
                int c = 16 * cj + l15;
                #pragma unroll
                for (int mj = 0; mj < 5; ++mj) {
                    int m = 80 * mg + 16 * mj + 4 * g;
                    *(f32x4*)(dst + c * 172 + m) = pacc[mj][cj];
                }
            }
        }
        __syncthreads();
        if ((sg & 1) == 1) {   // sg 1 / sg 3: accumulate
            #pragma unroll
            for (int cj = 0; cj < 4; ++cj) {
                int c = 16 * cj + l15;
                #pragma unroll
                for (int mj = 0; mj < 5; ++mj) {
                    int m = 80 * mg + 16 * mj + 4 * g;
                    float* p = dst + c * 172 + m;
                    f32x4 o = *(const f32x4*)p;
                    f32x4 v = pacc[mj][cj];
                    o[0] += v[0]; o[1] += v[1]; o[2] += v[2]; o[3] += v[3];
                    *(f32x4*)p = o;
                }
            }
        }
        __syncthreads();
    }

    // ---- dot partial = sum_m (A+B)^2 ; one atomic per (block, c) ----
    float* fred = (float*)(sm + RED1);
    {
        int c = tid & 63, g8 = wv;          // wave g8 handles m in [20*g8, 20*g8+20)
        float s = 0.f;
        #pragma unroll
        for (int j = 0; j < 5; ++j) {
            f32x4 va = *(const f32x4*)(w2rA + c * 172 + 20 * g8 + 4 * j);
            f32x4 vb = *(const f32x4*)(w2rB + c * 172 + 20 * g8 + 4 * j);
            #pragma unroll
            for (int e = 0; e < 4; ++e) {
                float v = va[e] + vb[e];
                s += v * v;
            }
        }
        fred[g8 * 64 + c] = s;
    }
    __syncthreads();
    if (tid < 64) {
        float t = 0.f;
        #pragma unroll
        for (int j = 0; j < 8; ++j) t += fred[j * 64 + tid];
        atomicAdd(out + b * nC + tid, t);
    }
}

extern "C" void kernel_launch(void* const* d_in, const int* in_sizes, int n_in,
                              void* d_out, int out_size, void* d_ws, size_t ws_size,
                              hipStream_t stream) {
    const float* ctx  = (const float*)d_in[0];   // [B,S,H]
    const float* resp = (const float*)d_in[1];   // [B,C,H]
    const float* pos  = (const float*)d_in[2];   // [M,H]
    const int*   mask = (const int*)d_in[3];     // [B,S]
    float* out = (float*)d_out;                  // [B,C]

    (void)hipFuncSetAttribute((const void*)fused,
                              hipFuncAttributeMaxDynamicSharedMemorySize, LDSB);
    (void)hipMemsetAsync(d_out, 0, (size_t)nB * nC * sizeof(float), stream);
    fused<<<nB * 2, 512, LDSB, stream>>>(ctx, resp, pos, mask, out);
}